// Round 6
// baseline (17809.932 us; speedup 1.0000x reference)
//
#include <hip/hip_runtime.h>

// FeedbackTransformerKV — persistent kernel, round 6.
// r5 structure (128 blocks = batch g x col-slice cs; cs==head==XCD; 9 group
// barriers/step) + bf16-packed weights. r5's 31MB/step FETCH was the fp32
// per-XCD weight slice (5.25MB) thrashing the 4MB L2 every step. Packing all
// weights bf16 2-along-K (prologue kernel) shrinks the slice to ~2.6MB ->
// L2-resident across steps; unpack is 2 bit-ops; each dword load carries 2
// MACs (half the loads per GEMV).

#define S_ 128
#define B_ 16
#define D_ 512
#define H_ 8
#define DK_ 64
#define DFF_ 2048
#define L_ 4
#define P_ 4096

#define NBLK 128
#define NTHR 512

struct FtkvParams {
  const float *x_seq, *w_query, *qpb, *kpe, *w_out, *b_out;
  const float *ln1_g, *ln1_b, *ln2_g, *ln2_b;
  const float *w_ff1, *b_ff1, *w_ff2, *b_ff2;
  const float *norm_g, *norm_b, *comb_w, *w_key, *w_value;
  float *out;
  float *dpart;   // [16 g][8 cs][512]  Wout partials
  float *dpart2;  // [16 g][8 cs][512]  FF partials
  float *memK;    // [16 g][8 h][128 slot][64]  fp32
  float *memV;    // [16 g][8 h][128 slot][64]  fp32
  const unsigned *wqp;  // [L*256 k2][512]  bf16x2 packed along k
  const unsigned *wop;  // [L*256 k2][512]
  const unsigned *w1p;  // [L*256 k2][2048]
  const unsigned *w2p;  // [L*1024 k2][512]
  const unsigned *wkp;  // [256 k2][512]
  const unsigned *wvp;  // [256 k2][512]
  unsigned int *bar;
};

__device__ __forceinline__ float cload(const float *p_) {
  return __hip_atomic_load(p_, __ATOMIC_RELAXED, __HIP_MEMORY_SCOPE_AGENT);
}
__device__ __forceinline__ void cstore(float *p_, float v) {
  __hip_atomic_store(p_, v, __ATOMIC_RELAXED, __HIP_MEMORY_SCOPE_AGENT);
}

__device__ __forceinline__ float waveRedSum(float v) {
#pragma unroll
  for (int off = 32; off; off >>= 1) v += __shfl_xor(v, off, 64);
  return v;
}
__device__ __forceinline__ float waveRedMax(float v) {
#pragma unroll
  for (int off = 32; off; off >>= 1) v = fmaxf(v, __shfl_xor(v, off, 64));
  return v;
}

// bf16x2 dword -> two fp32 (pure bit ops, no cvt)
#define UNPK(w, flo, fhi)                                     \
  float flo = __uint_as_float((unsigned)(w) << 16);           \
  float fhi = __uint_as_float((unsigned)(w) & 0xffff0000u);

// 8-block group barrier, monotonic epochs, no acquire fence.
__device__ __forceinline__ void gbarN(unsigned *arr, unsigned *rel,
                                      unsigned &epoch, unsigned n) {
  __syncthreads();
  const unsigned e = ++epoch;
  if (threadIdx.x == 0) {
    unsigned old = __hip_atomic_fetch_add(arr, 1u, __ATOMIC_RELEASE,
                                          __HIP_MEMORY_SCOPE_AGENT);
    if (old == e * n - 1u)
      __hip_atomic_store(rel, e, __ATOMIC_RELAXED, __HIP_MEMORY_SCOPE_AGENT);
    while (__hip_atomic_load(rel, __ATOMIC_RELAXED,
                             __HIP_MEMORY_SCOPE_AGENT) < e)
      __builtin_amdgcn_s_sleep(1);
  }
  __syncthreads();
}

__global__ void ftkv_init(unsigned *bar) {
  for (int i = threadIdx.x; i < 4096; i += 256) bar[i] = 0u;
}

__device__ __forceinline__ unsigned bf16rne(float x) {
  unsigned b = __float_as_uint(x);
  return (b + 0x7fffu + ((b >> 16) & 1u)) >> 16;
}

// Pack src[K][N] (fp32) -> dst[K/2][N] (bf16x2: lo=row 2k2, hi=row 2k2+1)
__global__ void ftkv_pack(const float *src, unsigned *dst, int n2, int N) {
  for (int i = blockIdx.x * blockDim.x + threadIdx.x; i < n2;
       i += gridDim.x * blockDim.x) {
    int k2 = i / N, n = i - k2 * N;
    float lo = src[(size_t)(2 * k2) * N + n];
    float hi = src[(size_t)(2 * k2 + 1) * N + n];
    dst[i] = bf16rne(lo) | (bf16rne(hi) << 16);
  }
}

#define LNSTATS(val, mu_, rs_)                                             \
  {                                                                        \
    float _s1 = waveRedSum(val), _s2 = waveRedSum((val) * (val));          \
    __syncthreads();                                                       \
    if (lane == 0) { sRed[wid] = _s1; sRed[8 + wid] = _s2; }               \
    __syncthreads();                                                       \
    if (tid == 0) {                                                        \
      float _a = 0.f, _c = 0.f;                                            \
      for (int _i = 0; _i < 8; ++_i) { _a += sRed[_i]; _c += sRed[8 + _i];}\
      float _mu = _a * (1.f / 512.f);                                      \
      float _var = _c * (1.f / 512.f) - _mu * _mu;                         \
      sRed[16] = _mu; sRed[17] = rsqrtf(_var + 1e-5f);                     \
    }                                                                      \
    __syncthreads();                                                       \
    mu_ = sRed[16]; rs_ = sRed[17];                                        \
  }

__global__ __launch_bounds__(NTHR, 2) void ftkv_main(FtkvParams p) {
  const int bid = blockIdx.x;
  const int tid = threadIdx.x;
  const int lane = tid & 63, wid = tid >> 6;
  const int g = bid >> 3;  // batch element (group)
  const int cs = bid & 7;  // col-slice == head == XCD

  __shared__ float sZ[512];
  __shared__ float sP[512];
  __shared__ float sH[256];
  __shared__ float sQ[64], sQB[64], sS[128], sRed[20];

  unsigned *garr = p.bar + g * 32;
  unsigned *grel = p.bar + 1024 + g * 32;
  unsigned gep = 0;

  float cw0 = p.comb_w[0], cw1 = p.comb_w[1], cw2 = p.comb_w[2],
        cw3 = p.comb_w[3], cw4 = p.comb_w[4];
  float cm = fmaxf(fmaxf(fmaxf(cw0, cw1), fmaxf(cw2, cw3)), cw4);
  float e0 = __expf(cw0 - cm), e1 = __expf(cw1 - cm), e2 = __expf(cw2 - cm),
        e3 = __expf(cw3 - cm), e4 = __expf(cw4 - cm);
  float einv = 1.0f / (e0 + e1 + e2 + e3 + e4);
  float comb0 = e0 * einv, comb1 = e1 * einv, comb2 = e2 * einv,
        comb3 = e3 * einv, comb4 = e4 * einv;

  float xr = p.x_seq[g * D_ + tid];
  float mr = comb0 * xr;

  const float *memKb = p.memK + ((size_t)(g * H_ + cs)) * S_ * DK_;
  const float *memVb = p.memV + ((size_t)(g * H_ + cs)) * S_ * DK_;

  for (int t = 0; t < S_; ++t) {
    for (int l = 0; l < L_; ++l) {
      // =================== Phase A: entry-update + attention ============
      if (l > 0) {
        float s = p.b_ff2[(l - 1) * D_ + tid];
#pragma unroll
        for (int c2 = 0; c2 < 8; ++c2)
          s += cload(&p.dpart2[((size_t)g * 8 + c2) * D_ + tid]);
        xr += s;
        const float cl = (l == 1) ? comb1 : (l == 2) ? comb2 : comb3;
        mr += cl * xr;
      }
      if (t > 0) {
        float mu, rs;
        LNSTATS(xr, mu, rs);
        sZ[tid] = (xr - mu) * rs * p.ln1_g[l * D_ + tid] +
                  p.ln1_b[l * D_ + tid];
        __syncthreads();
        // q projection, head cs: thread=(ks=wid, d=lane); k2 = 32 per ks
        {
          const unsigned *wq =
              p.wqp + ((size_t)(l * 256 + wid * 32)) * 512 + cs * 64 + lane;
          float acc = 0.f;
#pragma unroll 4
          for (int k2 = 0; k2 < 32; ++k2) {
            unsigned w = wq[(size_t)k2 * 512];
            UNPK(w, flo, fhi);
            acc += sZ[wid * 64 + 2 * k2] * flo + sZ[wid * 64 + 2 * k2 + 1] * fhi;
          }
          sP[tid] = acc;
        }
        __syncthreads();
        if (tid < 64) {
          float q = 0.f;
#pragma unroll
          for (int ks = 0; ks < 8; ++ks) q += sP[ks * 64 + tid];
          sQ[tid] = q;
          sQB[tid] = q + p.qpb[(l * H_ + cs) * 64 + tid];
        }
        __syncthreads();
        // scores: thread=(j=tid&127, ds=tid>>7)
        {
          int j = tid & 127, ds = tid >> 7;
          float acc = 0.f;
          if (j < t) {
            const float *mk = memKb + (size_t)j * 64 + ds * 16;
            const float *kp = p.kpe +
                (((size_t)l * P_ + (P_ - t + j)) * H_ + cs) * 64 + ds * 16;
#pragma unroll
            for (int ii = 0; ii < 16; ++ii)
              acc += sQB[ds * 16 + ii] * mk[ii] + sQ[ds * 16 + ii] * kp[ii];
          }
          sP[tid] = acc;
        }
        __syncthreads();
        if (tid < 128) {
          float sc = (sP[tid] + sP[tid + 128]) + (sP[tid + 256] + sP[tid + 384]);
          sS[tid] = (tid < t) ? sc * 0.125f : -1e30f;
        }
        __syncthreads();
        if (tid < 64) {
          float m = waveRedMax(fmaxf(sS[tid], sS[tid + 64]));
          if (tid == 0) sRed[18] = m;
        }
        __syncthreads();
        if (tid < 128)
          sS[tid] = (tid < t) ? __expf(sS[tid] - sRed[18]) : 0.f;
        __syncthreads();
        if (tid < 64) {
          float s = waveRedSum(sS[tid] + sS[tid + 64]);
          if (tid == 0) sRed[19] = s;
        }
        __syncthreads();
        // av: thread=(js=wid, d=lane)
        {
          int j0 = wid * 16, j1 = (j0 + 16 < t) ? (j0 + 16) : t;
          float acc = 0.f;
          const float *mv = memVb + lane;
          for (int j = j0; j < j1; ++j) acc += sS[j] * mv[(size_t)j * 64];
          sP[tid] = acc;
        }
        __syncthreads();
        if (tid < 64) {
          float a = 0.f;
#pragma unroll
          for (int js = 0; js < 8; ++js) a += sP[js * 64 + tid];
          sQ[tid] = a / sRed[19];  // av (head cs)
        }
        __syncthreads();
        // Wout partial: rows cs*64.., col=tid; k2 = 32
        {
          const unsigned *wo =
              p.wop + ((size_t)(l * 256 + cs * 32)) * 512 + tid;
          float acc = 0.f;
#pragma unroll 4
          for (int k2 = 0; k2 < 32; ++k2) {
            unsigned w = wo[(size_t)k2 * 512];
            UNPK(w, flo, fhi);
            acc += sQ[2 * k2] * flo + sQ[2 * k2 + 1] * fhi;
          }
          cstore(&p.dpart[((size_t)g * 8 + cs) * D_ + tid], acc);
        }
        gbarN(garr, grel, gep, 8);
      }

      // =================== Phase B: out-proj apply + LN2 + FF ===========
      if (t > 0) {
        float s = p.b_out[l * D_ + tid];
#pragma unroll
        for (int c2 = 0; c2 < 8; ++c2)
          s += cload(&p.dpart[((size_t)g * 8 + c2) * D_ + tid]);
        xr += s;
      }
      {
        float mu, rs;
        LNSTATS(xr, mu, rs);
        sZ[tid] = (xr - mu) * rs * p.ln2_g[l * D_ + tid] +
                  p.ln2_b[l * D_ + tid];
      }
      __syncthreads();
      // FF1 cols cs*256..+255: thread=(ks=tid>>8, c=tid&255); k2=128 per ks
      {
        int c = tid & 255, ks = tid >> 8;
        const unsigned *w1 =
            p.w1p + ((size_t)(l * 256 + ks * 128)) * DFF_ + cs * 256 + c;
        float acc = 0.f;
#pragma unroll 4
        for (int k2 = 0; k2 < 128; ++k2) {
          unsigned w = w1[(size_t)k2 * DFF_];
          UNPK(w, flo, fhi);
          acc += sZ[ks * 256 + 2 * k2] * flo + sZ[ks * 256 + 2 * k2 + 1] * fhi;
        }
        sP[tid] = acc;
      }
      __syncthreads();
      if (tid < 256) {
        float h = sP[tid] + sP[256 + tid] + p.b_ff1[l * DFF_ + cs * 256 + tid];
        sH[tid] = fmaxf(h, 0.f);
      }
      __syncthreads();
      // FF2 partial: h-rows cs*256..+255, col=tid; k2=128
      {
        const unsigned *w2 =
            p.w2p + ((size_t)(l * 1024 + cs * 128)) * 512 + tid;
        float acc = 0.f;
#pragma unroll 4
        for (int k2 = 0; k2 < 128; ++k2) {
          unsigned w = w2[(size_t)k2 * 512];
          UNPK(w, flo, fhi);
          acc += sH[2 * k2] * flo + sH[2 * k2 + 1] * fhi;
        }
        cstore(&p.dpart2[((size_t)g * 8 + cs) * D_ + tid], acc);
      }
      gbarN(garr, grel, gep, 8);
    } // layers

    // =================== Phase E: mem -> KV slot t; out[t]; next x ======
    {
      float s = p.b_ff2[3 * D_ + tid];
#pragma unroll
      for (int c2 = 0; c2 < 8; ++c2)
        s += cload(&p.dpart2[((size_t)g * 8 + c2) * D_ + tid]);
      xr += s;
      mr += comb4 * xr;
      sZ[tid] = mr;
    }
    __syncthreads();
    // K and V projections, cols cs*64..: thread=(kv=tid>>8, ks=(r>>6), d)
    {
      int r = tid & 255, kv = tid >> 8;
      int ks = r >> 6, d = r & 63;
      const unsigned *w = (kv ? p.wvp : p.wkp) +
                          ((size_t)(ks * 64)) * 512 + cs * 64 + d;
      float acc = 0.f;
#pragma unroll 4
      for (int k2 = 0; k2 < 64; ++k2) {
        unsigned ww = w[(size_t)k2 * 512];
        UNPK(ww, flo, fhi);
        acc += sZ[ks * 128 + 2 * k2] * flo + sZ[ks * 128 + 2 * k2 + 1] * fhi;
      }
      sP[tid] = acc;
    }
    __syncthreads();
    if (tid < 128) {
      int kv = tid >> 6, d = tid & 63;
      float v = 0.f;
#pragma unroll
      for (int ks = 0; ks < 4; ++ks) v += sP[kv * 256 + ks * 64 + d];
      float *dst = kv ? p.memV : p.memK;
      dst[((size_t)(g * H_ + cs)) * S_ * DK_ + (size_t)t * 64 + d] = v;
    }
    {
      float mu, rs;
      LNSTATS(xr, mu, rs);
      if ((tid >> 6) == cs)
        p.out[((size_t)t * B_ + g) * D_ + tid] =
            (xr - mu) * rs * p.norm_g[tid] + p.norm_b[tid];
    }
    if (t + 1 < S_) {
      xr = p.x_seq[((size_t)(t + 1) * B_ + g) * D_ + tid];
      mr = comb0 * xr;
    }
    gbarN(garr, grel, gep, 8);
  } // t
}

extern "C" void kernel_launch(void *const *d_in, const int *in_sizes, int n_in,
                              void *d_out, int out_size, void *d_ws,
                              size_t ws_size, hipStream_t stream) {
  (void)in_sizes; (void)n_in; (void)out_size; (void)ws_size;

  FtkvParams p;
  p.x_seq  = (const float *)d_in[0];
  p.w_query = (const float *)d_in[1];
  p.qpb    = (const float *)d_in[2];
  p.kpe    = (const float *)d_in[3];
  p.w_out  = (const float *)d_in[4];
  p.b_out  = (const float *)d_in[5];
  p.ln1_g  = (const float *)d_in[6];
  p.ln1_b  = (const float *)d_in[7];
  p.ln2_g  = (const float *)d_in[8];
  p.ln2_b  = (const float *)d_in[9];
  p.w_ff1  = (const float *)d_in[10];
  p.b_ff1  = (const float *)d_in[11];
  p.w_ff2  = (const float *)d_in[12];
  p.b_ff2  = (const float *)d_in[13];
  p.norm_g = (const float *)d_in[14];
  p.norm_b = (const float *)d_in[15];
  p.comb_w = (const float *)d_in[16];
  p.w_key  = (const float *)d_in[17];
  p.w_value = (const float *)d_in[18];
  p.out = (float *)d_out;

  char *ws = (char *)d_ws;
  p.bar = (unsigned int *)ws; // 16KB
  float *f = (float *)(ws + 16384);
  p.dpart  = f; f += B_ * 8 * D_;        // 64K floats
  p.dpart2 = f; f += B_ * 8 * D_;        // 64K floats
  p.memK   = f; f += B_ * H_ * S_ * DK_; // 1M floats
  p.memV   = f; f += B_ * H_ * S_ * DK_; // 1M floats
  unsigned *u = (unsigned *)f;
  unsigned *wqp = u; u += L_ * 256 * 512;   // 512K
  unsigned *wop = u; u += L_ * 256 * 512;   // 512K
  unsigned *w1p = u; u += L_ * 256 * DFF_;  // 2M
  unsigned *w2p = u; u += L_ * 1024 * 512;  // 2M
  unsigned *wkp = u; u += 256 * 512;        // 128K
  unsigned *wvp = u; u += 256 * 512;        // 128K
  p.wqp = wqp; p.wop = wop; p.w1p = w1p; p.w2p = w2p;
  p.wkp = wkp; p.wvp = wvp;
  // total ws use ≈ 8.6MB fp32 regions + 21MB packed ≈ 30MB

  ftkv_init<<<dim3(1), dim3(256), 0, stream>>>(p.bar);
  ftkv_pack<<<dim3(512), dim3(256), 0, stream>>>(p.w_query, wqp,
                                                 L_ * 256 * 512, 512);
  ftkv_pack<<<dim3(512), dim3(256), 0, stream>>>(p.w_out, wop,
                                                 L_ * 256 * 512, 512);
  ftkv_pack<<<dim3(512), dim3(256), 0, stream>>>(p.w_ff1, w1p,
                                                 L_ * 256 * DFF_, DFF_);
  ftkv_pack<<<dim3(512), dim3(256), 0, stream>>>(p.w_ff2, w2p,
                                                 L_ * 1024 * 512, 512);
  ftkv_pack<<<dim3(512), dim3(256), 0, stream>>>(p.w_key, wkp,
                                                 256 * 512, 512);
  ftkv_pack<<<dim3(512), dim3(256), 0, stream>>>(p.w_value, wvp,
                                                 256 * 512, 512);
  ftkv_main<<<dim3(NBLK), dim3(NTHR), 0, stream>>>(p);
}

// Round 7
// 15588.835 us; speedup vs baseline: 1.1425x; 1.1425x over previous
//
#include <hip/hip_runtime.h>

// FeedbackTransformerKV — persistent kernel, round 7.
// r6 structure (128 blocks = batch g x col-slice cs; cs==head==XCD; group
// barriers) but phase bodies re-engineered for LATENCY, which r6 proved is
// the binding constraint (cutting HBM traffic 2.5x changed nothing):
//  - 1024-thread blocks: 16 waves/CU (4/SIMD) instead of 8 (1/SIMD);
//    per-thread GEMV work halves.
//  - weights packed as [k8][col][uint4]: one 16B coalesced load = 8 bf16
//    weights (was 1 dword = 2), 4-8x fewer outstanding loads per GEMV.
//  - float4 loads for memK/kpe in scores.
//  - E-phase barrier removed (E is group-local after B's barrier; next
//    A-barrier provides the ordering) -> 8 group barriers/step.

#define S_ 128
#define B_ 16
#define D_ 512
#define H_ 8
#define DK_ 64
#define DFF_ 2048
#define L_ 4
#define P_ 4096

#define NBLK 128
#define NTHR 1024

struct FtkvParams {
  const float *x_seq, *w_query, *qpb, *kpe, *w_out, *b_out;
  const float *ln1_g, *ln1_b, *ln2_g, *ln2_b;
  const float *w_ff1, *b_ff1, *w_ff2, *b_ff2;
  const float *norm_g, *norm_b, *comb_w, *w_key, *w_value;
  float *out;
  float *dpart;   // [16 g][8 cs][512]
  float *dpart2;  // [16 g][8 cs][512]
  float *memK;    // [16 g][8 h][128 slot][64] fp32
  float *memV;    // [16 g][8 h][128 slot][64] fp32
  const uint4 *wqp;  // [64 k8][512 col]  (uint4 = 8 bf16 along k)
  const uint4 *wop;  // [64 k8][512] per layer stride 64*512
  const uint4 *w1p;  // [64 k8][2048] per layer
  const uint4 *w2p;  // [256 k8][512] per layer
  const uint4 *wkp;  // [64 k8][512]
  const uint4 *wvp;  // [64 k8][512]
  unsigned int *bar;
};

__device__ __forceinline__ float cload(const float *p_) {
  return __hip_atomic_load(p_, __ATOMIC_RELAXED, __HIP_MEMORY_SCOPE_AGENT);
}
__device__ __forceinline__ void cstore(float *p_, float v) {
  __hip_atomic_store(p_, v, __ATOMIC_RELAXED, __HIP_MEMORY_SCOPE_AGENT);
}

__device__ __forceinline__ float waveRedSum(float v) {
#pragma unroll
  for (int off = 32; off; off >>= 1) v += __shfl_xor(v, off, 64);
  return v;
}
__device__ __forceinline__ float waveRedMax(float v) {
#pragma unroll
  for (int off = 32; off; off >>= 1) v = fmaxf(v, __shfl_xor(v, off, 64));
  return v;
}

#define UNPK(w, flo, fhi)                                     \
  float flo = __uint_as_float((unsigned)(w) << 16);           \
  float fhi = __uint_as_float((unsigned)(w) & 0xffff0000u);

// dot of 8 consecutive activations with a uint4 (8 bf16 weights)
__device__ __forceinline__ float dot8(const float *z, uint4 w) {
  UNPK(w.x, a0, a1); UNPK(w.y, b0, b1);
  UNPK(w.z, c0, c1); UNPK(w.w, d0, d1);
  return ((z[0] * a0 + z[1] * a1) + (z[2] * b0 + z[3] * b1)) +
         ((z[4] * c0 + z[5] * c1) + (z[6] * d0 + z[7] * d1));
}

__device__ __forceinline__ void gbarN(unsigned *arr, unsigned *rel,
                                      unsigned &epoch, unsigned n) {
  __syncthreads();
  const unsigned e = ++epoch;
  if (threadIdx.x == 0) {
    unsigned old = __hip_atomic_fetch_add(arr, 1u, __ATOMIC_RELEASE,
                                          __HIP_MEMORY_SCOPE_AGENT);
    if (old == e * n - 1u)
      __hip_atomic_store(rel, e, __ATOMIC_RELAXED, __HIP_MEMORY_SCOPE_AGENT);
    while (__hip_atomic_load(rel, __ATOMIC_RELAXED,
                             __HIP_MEMORY_SCOPE_AGENT) < e)
      __builtin_amdgcn_s_sleep(1);
  }
  __syncthreads();
}

__global__ void ftkv_init(unsigned *bar) {
  for (int i = threadIdx.x; i < 4096; i += 256) bar[i] = 0u;
}

__device__ __forceinline__ unsigned bf16rne(float x) {
  unsigned b = __float_as_uint(x);
  return (b + 0x7fffu + ((b >> 16) & 1u)) >> 16;
}

// src[K][N] fp32 -> dst dwords laid out as [K/8][N][4]:
// dst[((k8*N)+col)*4+q] = bf16(src[8k8+2q][col]) | bf16(src[8k8+2q+1][col])<<16
__global__ void ftkv_pack(const float *src, unsigned *dst, int K, int N) {
  int total = (K / 2) * N;
  int n4 = N * 4;
  for (int i = blockIdx.x * blockDim.x + threadIdx.x; i < total;
       i += gridDim.x * blockDim.x) {
    int k8 = i / n4, rem = i - k8 * n4;
    int col = rem >> 2, q = rem & 3;
    int r0 = 8 * k8 + 2 * q;
    dst[i] = bf16rne(src[(size_t)r0 * N + col]) |
             (bf16rne(src[(size_t)(r0 + 1) * N + col]) << 16);
  }
}

#define LNSTATS(val, mu_, rs_)                                             \
  {                                                                        \
    __syncthreads();                                                       \
    if (tid < 512) {                                                       \
      float _s1 = waveRedSum(val), _s2 = waveRedSum((val) * (val));        \
      if (lane == 0) { sRed[wid] = _s1; sRed[8 + wid] = _s2; }             \
    }                                                                      \
    __syncthreads();                                                       \
    if (tid == 0) {                                                        \
      float _a = 0.f, _c = 0.f;                                            \
      for (int _i = 0; _i < 8; ++_i) { _a += sRed[_i]; _c += sRed[8 + _i];}\
      float _mu = _a * (1.f / 512.f);                                      \
      float _var = _c * (1.f / 512.f) - _mu * _mu;                         \
      sRed[16] = _mu; sRed[17] = rsqrtf(_var + 1e-5f);                     \
    }                                                                      \
    __syncthreads();                                                       \
    mu_ = sRed[16]; rs_ = sRed[17];                                        \
  }

__global__ __launch_bounds__(NTHR, 4) void ftkv_main(FtkvParams p) {
  const int bid = blockIdx.x;
  const int tid = threadIdx.x;
  const int lane = tid & 63, wid = tid >> 6;
  const int g = bid >> 3;  // batch element (group)
  const int cs = bid & 7;  // col-slice == head == XCD

  __shared__ float sZ[512];
  __shared__ float sP[1024];
  __shared__ float sH[256];
  __shared__ float sQ[64], sQB[64], sS[128], sRed[20];

  unsigned *garr = p.bar + g * 32;
  unsigned *grel = p.bar + 1024 + g * 32;
  unsigned gep = 0;

  float cw0 = p.comb_w[0], cw1 = p.comb_w[1], cw2 = p.comb_w[2],
        cw3 = p.comb_w[3], cw4 = p.comb_w[4];
  float cm = fmaxf(fmaxf(fmaxf(cw0, cw1), fmaxf(cw2, cw3)), cw4);
  float e0 = __expf(cw0 - cm), e1 = __expf(cw1 - cm), e2 = __expf(cw2 - cm),
        e3 = __expf(cw3 - cm), e4 = __expf(cw4 - cm);
  float einv = 1.0f / (e0 + e1 + e2 + e3 + e4);
  float comb0 = e0 * einv, comb1 = e1 * einv, comb2 = e2 * einv,
        comb3 = e3 * einv, comb4 = e4 * einv;

  // full x and macc copies in lower 512 threads (tid == column)
  float xr = 0.f, mr = 0.f;
  if (tid < 512) {
    xr = p.x_seq[g * D_ + tid];
    mr = comb0 * xr;
  }

  const float *memKb = p.memK + ((size_t)(g * H_ + cs)) * S_ * DK_;
  const float *memVb = p.memV + ((size_t)(g * H_ + cs)) * S_ * DK_;

  for (int t = 0; t < S_; ++t) {
    for (int l = 0; l < L_; ++l) {
      // ---- entry update: apply FF(l-1) partials; macc += comb[l]*x ----
      if (l > 0 && tid < 512) {
        float s = p.b_ff2[(l - 1) * D_ + tid];
#pragma unroll
        for (int c2 = 0; c2 < 8; ++c2)
          s += cload(&p.dpart2[((size_t)g * 8 + c2) * D_ + tid]);
        xr += s;
        const float cl = (l == 1) ? comb1 : (l == 2) ? comb2 : comb3;
        mr += cl * xr;
      }

      // =================== Phase A: attention (t>0) =====================
      if (t > 0) {
        float mu, rs;
        LNSTATS(xr, mu, rs);
        if (tid < 512)
          sZ[tid] = (xr - mu) * rs * p.ln1_g[l * D_ + tid] +
                    p.ln1_b[l * D_ + tid];
        __syncthreads();
        // q projection: thread=(d=tid&63, ks=tid>>6 in 0..15), 4 uint4 each
        {
          int d = tid & 63, ks = tid >> 6;
          const uint4 *wq = p.wqp + (size_t)l * 64 * 512 + cs * 64 + d;
          float acc = 0.f;
#pragma unroll
          for (int j = 0; j < 4; ++j) {
            int k8 = ks * 4 + j;
            acc += dot8(&sZ[8 * k8], wq[(size_t)k8 * 512]);
          }
          sP[tid] = acc;
        }
        __syncthreads();
        if (tid < 64) {
          float q = 0.f;
#pragma unroll
          for (int ks = 0; ks < 16; ++ks) q += sP[ks * 64 + tid];
          sQ[tid] = q;
          sQB[tid] = q + p.qpb[(l * H_ + cs) * 64 + tid];
        }
        __syncthreads();
        // scores: thread=(j=tid&127, ds=tid>>7 in 0..7), 8 dims each
        {
          int j = tid & 127, ds = tid >> 7;
          float acc = 0.f;
          if (j < t) {
            const float4 *mk =
                (const float4 *)(memKb + (size_t)j * 64 + ds * 8);
            const float4 *kp = (const float4 *)(p.kpe +
                (((size_t)l * P_ + (P_ - t + j)) * H_ + cs) * 64 + ds * 8);
            float4 a0 = mk[0], a1 = mk[1], b0 = kp[0], b1 = kp[1];
            const float *qb = &sQB[ds * 8], *qr = &sQ[ds * 8];
            acc = (qb[0] * a0.x + qb[1] * a0.y + qb[2] * a0.z + qb[3] * a0.w) +
                  (qb[4] * a1.x + qb[5] * a1.y + qb[6] * a1.z + qb[7] * a1.w) +
                  (qr[0] * b0.x + qr[1] * b0.y + qr[2] * b0.z + qr[3] * b0.w) +
                  (qr[4] * b1.x + qr[5] * b1.y + qr[6] * b1.z + qr[7] * b1.w);
          }
          sP[tid] = acc;
        }
        __syncthreads();
        if (tid < 128) {
          float sc = ((sP[tid] + sP[tid + 128]) + (sP[tid + 256] + sP[tid + 384])) +
                     ((sP[tid + 512] + sP[tid + 640]) + (sP[tid + 768] + sP[tid + 896]));
          sS[tid] = (tid < t) ? sc * 0.125f : -1e30f;
        }
        __syncthreads();
        if (tid < 64) {
          float m = waveRedMax(fmaxf(sS[tid], sS[tid + 64]));
          if (tid == 0) sRed[18] = m;
        }
        __syncthreads();
        if (tid < 128)
          sS[tid] = (tid < t) ? __expf(sS[tid] - sRed[18]) : 0.f;
        __syncthreads();
        if (tid < 64) {
          float s = waveRedSum(sS[tid] + sS[tid + 64]);
          if (tid == 0) sRed[19] = s;
        }
        __syncthreads();
        // av: thread=(d=tid&63, js=tid>>6 in 0..15), 8 slots each
        {
          int d = tid & 63, js = tid >> 6;
          int j0 = js * 8, j1 = (j0 + 8 < t) ? (j0 + 8) : t;
          float acc = 0.f;
          const float *mv = memVb + d;
          for (int j = j0; j < j1; ++j) acc += sS[j] * mv[(size_t)j * 64];
          sP[tid] = acc;
        }
        __syncthreads();
        if (tid < 64) {
          float a = 0.f;
#pragma unroll
          for (int js = 0; js < 16; ++js) a += sP[js * 64 + tid];
          sQ[tid] = a / sRed[19];  // av (head cs)
        }
        __syncthreads();
        // Wout partial: thread=(col=tid&511, ks=tid>>9 in 0..1), 4 uint4
        {
          int col = tid & 511, ks = tid >> 9;
          const uint4 *wo = p.wop + (size_t)l * 64 * 512 + col;
          float acc = 0.f;
#pragma unroll
          for (int j = 0; j < 4; ++j) {
            int k8l = ks * 4 + j;
            acc += dot8(&sQ[8 * k8l], wo[(size_t)(cs * 8 + k8l) * 512]);
          }
          sP[tid] = acc;
        }
        __syncthreads();
        if (tid < 512)
          cstore(&p.dpart[((size_t)g * 8 + cs) * D_ + tid],
                 sP[tid] + sP[512 + tid]);
        gbarN(garr, grel, gep, 8);
      }

      // =================== Phase B: out-proj apply + LN2 + FF ===========
      if (t > 0 && tid < 512) {
        float s = p.b_out[l * D_ + tid];
#pragma unroll
        for (int c2 = 0; c2 < 8; ++c2)
          s += cload(&p.dpart[((size_t)g * 8 + c2) * D_ + tid]);
        xr += s;
      }
      {
        float mu, rs;
        LNSTATS(xr, mu, rs);
        if (tid < 512)
          sZ[tid] = (xr - mu) * rs * p.ln2_g[l * D_ + tid] +
                    p.ln2_b[l * D_ + tid];
      }
      __syncthreads();
      // FF1: thread=(c=tid&255, ks=tid>>8 in 0..3), 16 uint4 each
      {
        int c = tid & 255, ks = tid >> 8;
        const uint4 *w1 = p.w1p + (size_t)l * 64 * DFF_ + cs * 256 + c;
        float acc = 0.f;
#pragma unroll 8
        for (int j = 0; j < 16; ++j) {
          int k8 = ks * 16 + j;
          acc += dot8(&sZ[8 * k8], w1[(size_t)k8 * DFF_]);
        }
        sP[tid] = acc;
      }
      __syncthreads();
      if (tid < 256) {
        float h = ((sP[tid] + sP[256 + tid]) + (sP[512 + tid] + sP[768 + tid])) +
                  p.b_ff1[l * DFF_ + cs * 256 + tid];
        sH[tid] = fmaxf(h, 0.f);
      }
      __syncthreads();
      // FF2 partial: thread=(col=tid&511, ks=tid>>9 in 0..1), 16 uint4
      {
        int col = tid & 511, ks = tid >> 9;
        const uint4 *w2 = p.w2p + (size_t)l * 256 * 512 + col;
        float acc = 0.f;
#pragma unroll 8
        for (int j = 0; j < 16; ++j) {
          int k8l = ks * 16 + j;
          acc += dot8(&sH[8 * k8l], w2[(size_t)(cs * 32 + k8l) * 512]);
        }
        sP[tid] = acc;
      }
      __syncthreads();
      if (tid < 512)
        cstore(&p.dpart2[((size_t)g * 8 + cs) * D_ + tid],
               sP[tid] + sP[512 + tid]);
      gbarN(garr, grel, gep, 8);
    } // layers

    // ====== Phase E (group-local, no barrier): KV slot t; out; next x ====
    if (tid < 512) {
      float s = p.b_ff2[3 * D_ + tid];
#pragma unroll
      for (int c2 = 0; c2 < 8; ++c2)
        s += cload(&p.dpart2[((size_t)g * 8 + c2) * D_ + tid]);
      xr += s;
      mr += comb4 * xr;
      sZ[tid] = mr;
    }
    __syncthreads();
    // K/V proj: thread=(kv=tid>>9, r=tid&511 -> d=r&63, ks=r>>6), 8 uint4
    {
      int kv = tid >> 9, r = tid & 511, d = r & 63, ks = r >> 6;
      const uint4 *w4 = (kv ? p.wvp : p.wkp) + cs * 64 + d;
      float acc = 0.f;
#pragma unroll
      for (int j = 0; j < 8; ++j) {
        int k8 = ks * 8 + j;
        acc += dot8(&sZ[8 * k8], w4[(size_t)k8 * 512]);
      }
      sP[tid] = acc;
    }
    __syncthreads();
    if (tid < 128) {
      int kv = tid >> 6, d = tid & 63;
      float v = 0.f;
#pragma unroll
      for (int ks = 0; ks < 8; ++ks) v += sP[kv * 512 + ks * 64 + d];
      float *dst = kv ? p.memV : p.memK;
      dst[((size_t)(g * H_ + cs)) * S_ * DK_ + (size_t)t * 64 + d] = v;
    }
    {
      float mu, rs;
      LNSTATS(xr, mu, rs);
      if (tid < 512 && (tid >> 6) == cs)
        p.out[((size_t)t * B_ + g) * D_ + tid] =
            (xr - mu) * rs * p.norm_g[tid] + p.norm_b[tid];
    }
    if (t + 1 < S_ && tid < 512) {
      xr = p.x_seq[((size_t)(t + 1) * B_ + g) * D_ + tid];
      mr = comb0 * xr;
    }
    // no barrier: E is group-local; next A-barrier orders everything
  } // t
}

extern "C" void kernel_launch(void *const *d_in, const int *in_sizes, int n_in,
                              void *d_out, int out_size, void *d_ws,
                              size_t ws_size, hipStream_t stream) {
  (void)in_sizes; (void)n_in; (void)out_size; (void)ws_size;

  FtkvParams p;
  p.x_seq  = (const float *)d_in[0];
  p.w_query = (const float *)d_in[1];
  p.qpb    = (const float *)d_in[2];
  p.kpe    = (const float *)d_in[3];
  p.w_out  = (const float *)d_in[4];
  p.b_out  = (const float *)d_in[5];
  p.ln1_g  = (const float *)d_in[6];
  p.ln1_b  = (const float *)d_in[7];
  p.ln2_g  = (const float *)d_in[8];
  p.ln2_b  = (const float *)d_in[9];
  p.w_ff1  = (const float *)d_in[10];
  p.b_ff1  = (const float *)d_in[11];
  p.w_ff2  = (const float *)d_in[12];
  p.b_ff2  = (const float *)d_in[13];
  p.norm_g = (const float *)d_in[14];
  p.norm_b = (const float *)d_in[15];
  p.comb_w = (const float *)d_in[16];
  p.w_key  = (const float *)d_in[17];
  p.w_value = (const float *)d_in[18];
  p.out = (float *)d_out;

  char *ws = (char *)d_ws;
  p.bar = (unsigned int *)ws; // 16KB
  float *f = (float *)(ws + 16384);
  p.dpart  = f; f += B_ * 8 * D_;
  p.dpart2 = f; f += B_ * 8 * D_;
  p.memK   = f; f += B_ * H_ * S_ * DK_;
  p.memV   = f; f += B_ * H_ * S_ * DK_;
  unsigned *u = (unsigned *)f;
  unsigned *wqp = u; u += L_ * 256 * 512;   // dword counts (K/2 * N)
  unsigned *wop = u; u += L_ * 256 * 512;
  unsigned *w1p = u; u += L_ * 256 * DFF_;
  unsigned *w2p = u; u += L_ * 1024 * 512;
  unsigned *wkp = u; u += 256 * 512;
  unsigned *wvp = u; u += 256 * 512;
  p.wqp = (const uint4 *)wqp; p.wop = (const uint4 *)wop;
  p.w1p = (const uint4 *)w1p; p.w2p = (const uint4 *)w2p;
  p.wkp = (const uint4 *)wkp; p.wvp = (const uint4 *)wvp;

  ftkv_init<<<dim3(1), dim3(256), 0, stream>>>(p.bar);
  // per-layer packing (layouts are per-layer [K/8][N][4])
  for (int l = 0; l < L_; ++l) {
    ftkv_pack<<<dim3(256), dim3(256), 0, stream>>>(
        p.w_query + (size_t)l * 512 * 512, wqp + (size_t)l * 256 * 512, 512, 512);
    ftkv_pack<<<dim3(256), dim3(256), 0, stream>>>(
        p.w_out + (size_t)l * 512 * 512, wop + (size_t)l * 256 * 512, 512, 512);
    ftkv_pack<<<dim3(512), dim3(256), 0, stream>>>(
        p.w_ff1 + (size_t)l * 512 * DFF_, w1p + (size_t)l * 256 * DFF_, 512, DFF_);
    ftkv_pack<<<dim3(512), dim3(256), 0, stream>>>(
        p.w_ff2 + (size_t)l * DFF_ * 512, w2p + (size_t)l * 1024 * 512, DFF_, 512);
  }
  ftkv_pack<<<dim3(256), dim3(256), 0, stream>>>(p.w_key, wkp, 512, 512);
  ftkv_pack<<<dim3(256), dim3(256), 0, stream>>>(p.w_value, wvp, 512, 512);
  ftkv_main<<<dim3(NBLK), dim3(NTHR), 0, stream>>>(p);
}

// Round 8
// 14588.928 us; speedup vs baseline: 1.2208x; 1.0685x over previous
//
#include <hip/hip_runtime.h>

// FeedbackTransformerKV — persistent kernel, round 8.
// r7 structure unchanged. ONE change: the group-barrier arrive was a
// RELEASE agent-scope fetch_add; on gfx950 that emits buffer_wbl2 sc1 (full
// per-XCD L2 writeback walk) before the atomic. 128 blocks x 8 phases/step
// => ~16 serialized L2 walks per XCD per phase ~= the pinned ~15us/phase
// seen in r5/r6/r7. All cross-block data already goes through sc1
// write-through stores drained by __syncthreads (never dirty in L2), so the
// arrive can be RELAXED -> no cache maintenance at all.

#define S_ 128
#define B_ 16
#define D_ 512
#define H_ 8
#define DK_ 64
#define DFF_ 2048
#define L_ 4
#define P_ 4096

#define NBLK 128
#define NTHR 1024

struct FtkvParams {
  const float *x_seq, *w_query, *qpb, *kpe, *w_out, *b_out;
  const float *ln1_g, *ln1_b, *ln2_g, *ln2_b;
  const float *w_ff1, *b_ff1, *w_ff2, *b_ff2;
  const float *norm_g, *norm_b, *comb_w, *w_key, *w_value;
  float *out;
  float *dpart;   // [16 g][8 cs][512]
  float *dpart2;  // [16 g][8 cs][512]
  float *memK;    // [16 g][8 h][128 slot][64] fp32
  float *memV;    // [16 g][8 h][128 slot][64] fp32
  const uint4 *wqp;  // [64 k8][512 col]  (uint4 = 8 bf16 along k)
  const uint4 *wop;  // [64 k8][512] per layer stride 64*512
  const uint4 *w1p;  // [64 k8][2048] per layer
  const uint4 *w2p;  // [256 k8][512] per layer
  const uint4 *wkp;  // [64 k8][512]
  const uint4 *wvp;  // [64 k8][512]
  unsigned int *bar;
};

__device__ __forceinline__ float cload(const float *p_) {
  return __hip_atomic_load(p_, __ATOMIC_RELAXED, __HIP_MEMORY_SCOPE_AGENT);
}
__device__ __forceinline__ void cstore(float *p_, float v) {
  __hip_atomic_store(p_, v, __ATOMIC_RELAXED, __HIP_MEMORY_SCOPE_AGENT);
}

__device__ __forceinline__ float waveRedSum(float v) {
#pragma unroll
  for (int off = 32; off; off >>= 1) v += __shfl_xor(v, off, 64);
  return v;
}
__device__ __forceinline__ float waveRedMax(float v) {
#pragma unroll
  for (int off = 32; off; off >>= 1) v = fmaxf(v, __shfl_xor(v, off, 64));
  return v;
}

#define UNPK(w, flo, fhi)                                     \
  float flo = __uint_as_float((unsigned)(w) << 16);           \
  float fhi = __uint_as_float((unsigned)(w) & 0xffff0000u);

// dot of 8 consecutive activations with a uint4 (8 bf16 weights)
__device__ __forceinline__ float dot8(const float *z, uint4 w) {
  UNPK(w.x, a0, a1); UNPK(w.y, b0, b1);
  UNPK(w.z, c0, c1); UNPK(w.w, d0, d1);
  return ((z[0] * a0 + z[1] * a1) + (z[2] * b0 + z[3] * b1)) +
         ((z[4] * c0 + z[5] * c1) + (z[6] * d0 + z[7] * d1));
}

// Group barrier: RELAXED arrive (no wbl2/inv — data path is sc1
// write-through, drained by the __syncthreads vmcnt(0) before arrive).
__device__ __forceinline__ void gbarN(unsigned *arr, unsigned *rel,
                                      unsigned &epoch, unsigned n) {
  __syncthreads();
  const unsigned e = ++epoch;
  if (threadIdx.x == 0) {
    unsigned old = __hip_atomic_fetch_add(arr, 1u, __ATOMIC_RELAXED,
                                          __HIP_MEMORY_SCOPE_AGENT);
    if (old == e * n - 1u)
      __hip_atomic_store(rel, e, __ATOMIC_RELAXED, __HIP_MEMORY_SCOPE_AGENT);
    while (__hip_atomic_load(rel, __ATOMIC_RELAXED,
                             __HIP_MEMORY_SCOPE_AGENT) < e)
      __builtin_amdgcn_s_sleep(1);
  }
  __syncthreads();
}

__global__ void ftkv_init(unsigned *bar) {
  for (int i = threadIdx.x; i < 4096; i += 256) bar[i] = 0u;
}

__device__ __forceinline__ unsigned bf16rne(float x) {
  unsigned b = __float_as_uint(x);
  return (b + 0x7fffu + ((b >> 16) & 1u)) >> 16;
}

// src[K][N] fp32 -> dst dwords laid out as [K/8][N][4]:
// dst[((k8*N)+col)*4+q] = bf16(src[8k8+2q][col]) | bf16(src[8k8+2q+1][col])<<16
__global__ void ftkv_pack(const float *src, unsigned *dst, int K, int N) {
  int total = (K / 2) * N;
  int n4 = N * 4;
  for (int i = blockIdx.x * blockDim.x + threadIdx.x; i < total;
       i += gridDim.x * blockDim.x) {
    int k8 = i / n4, rem = i - k8 * n4;
    int col = rem >> 2, q = rem & 3;
    int r0 = 8 * k8 + 2 * q;
    dst[i] = bf16rne(src[(size_t)r0 * N + col]) |
             (bf16rne(src[(size_t)(r0 + 1) * N + col]) << 16);
  }
}

#define LNSTATS(val, mu_, rs_)                                             \
  {                                                                        \
    __syncthreads();                                                       \
    if (tid < 512) {                                                       \
      float _s1 = waveRedSum(val), _s2 = waveRedSum((val) * (val));        \
      if (lane == 0) { sRed[wid] = _s1; sRed[8 + wid] = _s2; }             \
    }                                                                      \
    __syncthreads();                                                       \
    if (tid == 0) {                                                        \
      float _a = 0.f, _c = 0.f;                                            \
      for (int _i = 0; _i < 8; ++_i) { _a += sRed[_i]; _c += sRed[8 + _i];}\
      float _mu = _a * (1.f / 512.f);                                      \
      float _var = _c * (1.f / 512.f) - _mu * _mu;                         \
      sRed[16] = _mu; sRed[17] = rsqrtf(_var + 1e-5f);                     \
    }                                                                      \
    __syncthreads();                                                       \
    mu_ = sRed[16]; rs_ = sRed[17];                                        \
  }

__global__ __launch_bounds__(NTHR, 4) void ftkv_main(FtkvParams p) {
  const int bid = blockIdx.x;
  const int tid = threadIdx.x;
  const int lane = tid & 63, wid = tid >> 6;
  const int g = bid >> 3;  // batch element (group)
  const int cs = bid & 7;  // col-slice == head == XCD

  __shared__ float sZ[512];
  __shared__ float sP[1024];
  __shared__ float sH[256];
  __shared__ float sQ[64], sQB[64], sS[128], sRed[20];

  unsigned *garr = p.bar + g * 32;
  unsigned *grel = p.bar + 1024 + g * 32;
  unsigned gep = 0;

  float cw0 = p.comb_w[0], cw1 = p.comb_w[1], cw2 = p.comb_w[2],
        cw3 = p.comb_w[3], cw4 = p.comb_w[4];
  float cm = fmaxf(fmaxf(fmaxf(cw0, cw1), fmaxf(cw2, cw3)), cw4);
  float e0 = __expf(cw0 - cm), e1 = __expf(cw1 - cm), e2 = __expf(cw2 - cm),
        e3 = __expf(cw3 - cm), e4 = __expf(cw4 - cm);
  float einv = 1.0f / (e0 + e1 + e2 + e3 + e4);
  float comb0 = e0 * einv, comb1 = e1 * einv, comb2 = e2 * einv,
        comb3 = e3 * einv, comb4 = e4 * einv;

  // full x and macc copies in lower 512 threads (tid == column)
  float xr = 0.f, mr = 0.f;
  if (tid < 512) {
    xr = p.x_seq[g * D_ + tid];
    mr = comb0 * xr;
  }

  const float *memKb = p.memK + ((size_t)(g * H_ + cs)) * S_ * DK_;
  const float *memVb = p.memV + ((size_t)(g * H_ + cs)) * S_ * DK_;

  for (int t = 0; t < S_; ++t) {
    for (int l = 0; l < L_; ++l) {
      // ---- entry update: apply FF(l-1) partials; macc += comb[l]*x ----
      if (l > 0 && tid < 512) {
        float s = p.b_ff2[(l - 1) * D_ + tid];
#pragma unroll
        for (int c2 = 0; c2 < 8; ++c2)
          s += cload(&p.dpart2[((size_t)g * 8 + c2) * D_ + tid]);
        xr += s;
        const float cl = (l == 1) ? comb1 : (l == 2) ? comb2 : comb3;
        mr += cl * xr;
      }

      // =================== Phase A: attention (t>0) =====================
      if (t > 0) {
        float mu, rs;
        LNSTATS(xr, mu, rs);
        if (tid < 512)
          sZ[tid] = (xr - mu) * rs * p.ln1_g[l * D_ + tid] +
                    p.ln1_b[l * D_ + tid];
        __syncthreads();
        // q projection: thread=(d=tid&63, ks=tid>>6 in 0..15), 4 uint4 each
        {
          int d = tid & 63, ks = tid >> 6;
          const uint4 *wq = p.wqp + (size_t)l * 64 * 512 + cs * 64 + d;
          float acc = 0.f;
#pragma unroll
          for (int j = 0; j < 4; ++j) {
            int k8 = ks * 4 + j;
            acc += dot8(&sZ[8 * k8], wq[(size_t)k8 * 512]);
          }
          sP[tid] = acc;
        }
        __syncthreads();
        if (tid < 64) {
          float q = 0.f;
#pragma unroll
          for (int ks = 0; ks < 16; ++ks) q += sP[ks * 64 + tid];
          sQ[tid] = q;
          sQB[tid] = q + p.qpb[(l * H_ + cs) * 64 + tid];
        }
        __syncthreads();
        // scores: thread=(j=tid&127, ds=tid>>7 in 0..7), 8 dims each
        {
          int j = tid & 127, ds = tid >> 7;
          float acc = 0.f;
          if (j < t) {
            const float4 *mk =
                (const float4 *)(memKb + (size_t)j * 64 + ds * 8);
            const float4 *kp = (const float4 *)(p.kpe +
                (((size_t)l * P_ + (P_ - t + j)) * H_ + cs) * 64 + ds * 8);
            float4 a0 = mk[0], a1 = mk[1], b0 = kp[0], b1 = kp[1];
            const float *qb = &sQB[ds * 8], *qr = &sQ[ds * 8];
            acc = (qb[0] * a0.x + qb[1] * a0.y + qb[2] * a0.z + qb[3] * a0.w) +
                  (qb[4] * a1.x + qb[5] * a1.y + qb[6] * a1.z + qb[7] * a1.w) +
                  (qr[0] * b0.x + qr[1] * b0.y + qr[2] * b0.z + qr[3] * b0.w) +
                  (qr[4] * b1.x + qr[5] * b1.y + qr[6] * b1.z + qr[7] * b1.w);
          }
          sP[tid] = acc;
        }
        __syncthreads();
        if (tid < 128) {
          float sc = ((sP[tid] + sP[tid + 128]) + (sP[tid + 256] + sP[tid + 384])) +
                     ((sP[tid + 512] + sP[tid + 640]) + (sP[tid + 768] + sP[tid + 896]));
          sS[tid] = (tid < t) ? sc * 0.125f : -1e30f;
        }
        __syncthreads();
        if (tid < 64) {
          float m = waveRedMax(fmaxf(sS[tid], sS[tid + 64]));
          if (tid == 0) sRed[18] = m;
        }
        __syncthreads();
        if (tid < 128)
          sS[tid] = (tid < t) ? __expf(sS[tid] - sRed[18]) : 0.f;
        __syncthreads();
        if (tid < 64) {
          float s = waveRedSum(sS[tid] + sS[tid + 64]);
          if (tid == 0) sRed[19] = s;
        }
        __syncthreads();
        // av: thread=(d=tid&63, js=tid>>6 in 0..15), 8 slots each
        {
          int d = tid & 63, js = tid >> 6;
          int j0 = js * 8, j1 = (j0 + 8 < t) ? (j0 + 8) : t;
          float acc = 0.f;
          const float *mv = memVb + d;
          for (int j = j0; j < j1; ++j) acc += sS[j] * mv[(size_t)j * 64];
          sP[tid] = acc;
        }
        __syncthreads();
        if (tid < 64) {
          float a = 0.f;
#pragma unroll
          for (int js = 0; js < 16; ++js) a += sP[js * 64 + tid];
          sQ[tid] = a / sRed[19];  // av (head cs)
        }
        __syncthreads();
        // Wout partial: thread=(col=tid&511, ks=tid>>9 in 0..1), 4 uint4
        {
          int col = tid & 511, ks = tid >> 9;
          const uint4 *wo = p.wop + (size_t)l * 64 * 512 + col;
          float acc = 0.f;
#pragma unroll
          for (int j = 0; j < 4; ++j) {
            int k8l = ks * 4 + j;
            acc += dot8(&sQ[8 * k8l], wo[(size_t)(cs * 8 + k8l) * 512]);
          }
          sP[tid] = acc;
        }
        __syncthreads();
        if (tid < 512)
          cstore(&p.dpart[((size_t)g * 8 + cs) * D_ + tid],
                 sP[tid] + sP[512 + tid]);
        gbarN(garr, grel, gep, 8);
      }

      // =================== Phase B: out-proj apply + LN2 + FF ===========
      if (t > 0 && tid < 512) {
        float s = p.b_out[l * D_ + tid];
#pragma unroll
        for (int c2 = 0; c2 < 8; ++c2)
          s += cload(&p.dpart[((size_t)g * 8 + c2) * D_ + tid]);
        xr += s;
      }
      {
        float mu, rs;
        LNSTATS(xr, mu, rs);
        if (tid < 512)
          sZ[tid] = (xr - mu) * rs * p.ln2_g[l * D_ + tid] +
                    p.ln2_b[l * D_ + tid];
      }
      __syncthreads();
      // FF1: thread=(c=tid&255, ks=tid>>8 in 0..3), 16 uint4 each
      {
        int c = tid & 255, ks = tid >> 8;
        const uint4 *w1 = p.w1p + (size_t)l * 64 * DFF_ + cs * 256 + c;
        float acc = 0.f;
#pragma unroll 8
        for (int j = 0; j < 16; ++j) {
          int k8 = ks * 16 + j;
          acc += dot8(&sZ[8 * k8], w1[(size_t)k8 * DFF_]);
        }
        sP[tid] = acc;
      }
      __syncthreads();
      if (tid < 256) {
        float h = ((sP[tid] + sP[256 + tid]) + (sP[512 + tid] + sP[768 + tid])) +
                  p.b_ff1[l * DFF_ + cs * 256 + tid];
        sH[tid] = fmaxf(h, 0.f);
      }
      __syncthreads();
      // FF2 partial: thread=(col=tid&511, ks=tid>>9 in 0..1), 16 uint4
      {
        int col = tid & 511, ks = tid >> 9;
        const uint4 *w2 = p.w2p + (size_t)l * 256 * 512 + col;
        float acc = 0.f;
#pragma unroll 8
        for (int j = 0; j < 16; ++j) {
          int k8l = ks * 16 + j;
          acc += dot8(&sH[8 * k8l], w2[(size_t)(cs * 32 + k8l) * 512]);
        }
        sP[tid] = acc;
      }
      __syncthreads();
      if (tid < 512)
        cstore(&p.dpart2[((size_t)g * 8 + cs) * D_ + tid],
               sP[tid] + sP[512 + tid]);
      gbarN(garr, grel, gep, 8);
    } // layers

    // ====== Phase E (group-local, no barrier): KV slot t; out; next x ====
    if (tid < 512) {
      float s = p.b_ff2[3 * D_ + tid];
#pragma unroll
      for (int c2 = 0; c2 < 8; ++c2)
        s += cload(&p.dpart2[((size_t)g * 8 + c2) * D_ + tid]);
      xr += s;
      mr += comb4 * xr;
      sZ[tid] = mr;
    }
    __syncthreads();
    // K/V proj: thread=(kv=tid>>9, r=tid&511 -> d=r&63, ks=r>>6), 8 uint4
    {
      int kv = tid >> 9, r = tid & 511, d = r & 63, ks = r >> 6;
      const uint4 *w4 = (kv ? p.wvp : p.wkp) + cs * 64 + d;
      float acc = 0.f;
#pragma unroll
      for (int j = 0; j < 8; ++j) {
        int k8 = ks * 8 + j;
        acc += dot8(&sZ[8 * k8], w4[(size_t)k8 * 512]);
      }
      sP[tid] = acc;
    }
    __syncthreads();
    if (tid < 128) {
      int kv = tid >> 6, d = tid & 63;
      float v = 0.f;
#pragma unroll
      for (int ks = 0; ks < 8; ++ks) v += sP[kv * 512 + ks * 64 + d];
      float *dst = kv ? p.memV : p.memK;
      dst[((size_t)(g * H_ + cs)) * S_ * DK_ + (size_t)t * 64 + d] = v;
    }
    {
      float mu, rs;
      LNSTATS(xr, mu, rs);
      if (tid < 512 && (tid >> 6) == cs)
        p.out[((size_t)t * B_ + g) * D_ + tid] =
            (xr - mu) * rs * p.norm_g[tid] + p.norm_b[tid];
    }
    if (t + 1 < S_ && tid < 512) {
      xr = p.x_seq[((size_t)(t + 1) * B_ + g) * D_ + tid];
      mr = comb0 * xr;
    }
    // no barrier: E is group-local; next A-barrier orders everything
  } // t
}

extern "C" void kernel_launch(void *const *d_in, const int *in_sizes, int n_in,
                              void *d_out, int out_size, void *d_ws,
                              size_t ws_size, hipStream_t stream) {
  (void)in_sizes; (void)n_in; (void)out_size; (void)ws_size;

  FtkvParams p;
  p.x_seq  = (const float *)d_in[0];
  p.w_query = (const float *)d_in[1];
  p.qpb    = (const float *)d_in[2];
  p.kpe    = (const float *)d_in[3];
  p.w_out  = (const float *)d_in[4];
  p.b_out  = (const float *)d_in[5];
  p.ln1_g  = (const float *)d_in[6];
  p.ln1_b  = (const float *)d_in[7];
  p.ln2_g  = (const float *)d_in[8];
  p.ln2_b  = (const float *)d_in[9];
  p.w_ff1  = (const float *)d_in[10];
  p.b_ff1  = (const float *)d_in[11];
  p.w_ff2  = (const float *)d_in[12];
  p.b_ff2  = (const float *)d_in[13];
  p.norm_g = (const float *)d_in[14];
  p.norm_b = (const float *)d_in[15];
  p.comb_w = (const float *)d_in[16];
  p.w_key  = (const float *)d_in[17];
  p.w_value = (const float *)d_in[18];
  p.out = (float *)d_out;

  char *ws = (char *)d_ws;
  p.bar = (unsigned int *)ws; // 16KB
  float *f = (float *)(ws + 16384);
  p.dpart  = f; f += B_ * 8 * D_;
  p.dpart2 = f; f += B_ * 8 * D_;
  p.memK   = f; f += B_ * H_ * S_ * DK_;
  p.memV   = f; f += B_ * H_ * S_ * DK_;
  unsigned *u = (unsigned *)f;
  unsigned *wqp = u; u += L_ * 256 * 512;   // dword counts (K/2 * N)
  unsigned *wop = u; u += L_ * 256 * 512;
  unsigned *w1p = u; u += L_ * 256 * DFF_;
  unsigned *w2p = u; u += L_ * 1024 * 512;
  unsigned *wkp = u; u += 256 * 512;
  unsigned *wvp = u; u += 256 * 512;
  p.wqp = (const uint4 *)wqp; p.wop = (const uint4 *)wop;
  p.w1p = (const uint4 *)w1p; p.w2p = (const uint4 *)w2p;
  p.wkp = (const uint4 *)wkp; p.wvp = (const uint4 *)wvp;

  ftkv_init<<<dim3(1), dim3(256), 0, stream>>>(p.bar);
  for (int l = 0; l < L_; ++l) {
    ftkv_pack<<<dim3(256), dim3(256), 0, stream>>>(
        p.w_query + (size_t)l * 512 * 512, wqp + (size_t)l * 256 * 512, 512, 512);
    ftkv_pack<<<dim3(256), dim3(256), 0, stream>>>(
        p.w_out + (size_t)l * 512 * 512, wop + (size_t)l * 256 * 512, 512, 512);
    ftkv_pack<<<dim3(512), dim3(256), 0, stream>>>(
        p.w_ff1 + (size_t)l * 512 * DFF_, w1p + (size_t)l * 256 * DFF_, 512, DFF_);
    ftkv_pack<<<dim3(512), dim3(256), 0, stream>>>(
        p.w_ff2 + (size_t)l * DFF_ * 512, w2p + (size_t)l * 1024 * 512, DFF_, 512);
  }
  ftkv_pack<<<dim3(256), dim3(256), 0, stream>>>(p.w_key, wkp, 512, 512);
  ftkv_pack<<<dim3(256), dim3(256), 0, stream>>>(p.w_value, wvp, 512, 512);
  ftkv_main<<<dim3(NBLK), dim3(NTHR), 0, stream>>>(p);
}

// Round 9
// 14259.337 us; speedup vs baseline: 1.2490x; 1.0231x over previous
//
#include <hip/hip_runtime.h>

// FeedbackTransformerKV — persistent kernel, round 9.
// r8 structure. Two changes:
//  1) memK/memV stored as bf16 pairs (packed dwords): per-XCD working set
//     drops ~1MB -> weights (2.7MB) + KV (0.5MB) fit the 4MB L2; r8's
//     FETCH showed the whole 3.7MB/XCD set re-fetched every step (capacity
//     thrash) putting 2-3 MALL RTs in every GEMV body.
//  2) barrier waiters poll the arrive counter directly (arr >= epoch*n):
//     removes the release-store hop (-1 MALL RT per phase).

#define S_ 128
#define B_ 16
#define D_ 512
#define H_ 8
#define DK_ 64
#define DFF_ 2048
#define L_ 4
#define P_ 4096

#define NBLK 128
#define NTHR 1024

struct FtkvParams {
  const float *x_seq, *w_query, *qpb, *kpe, *w_out, *b_out;
  const float *ln1_g, *ln1_b, *ln2_g, *ln2_b;
  const float *w_ff1, *b_ff1, *w_ff2, *b_ff2;
  const float *norm_g, *norm_b, *comb_w, *w_key, *w_value;
  float *out;
  float *dpart;     // [16 g][8 cs][512]
  float *dpart2;    // [16 g][8 cs][512]
  unsigned *memK;   // [16 g][8 h][128 slot][32 dw]  bf16 pairs (dims 2q,2q+1)
  unsigned *memV;   // [16 g][8 h][128 slot][32 dw]
  const uint4 *wqp;  // [64 k8][512 col]  (uint4 = 8 bf16 along k)
  const uint4 *wop;  // per layer stride 64*512
  const uint4 *w1p;  // per layer [64 k8][2048]
  const uint4 *w2p;  // per layer [256 k8][512]
  const uint4 *wkp;  // [64 k8][512]
  const uint4 *wvp;  // [64 k8][512]
  unsigned int *bar;
};

__device__ __forceinline__ float cload(const float *p_) {
  return __hip_atomic_load(p_, __ATOMIC_RELAXED, __HIP_MEMORY_SCOPE_AGENT);
}
__device__ __forceinline__ void cstore(float *p_, float v) {
  __hip_atomic_store(p_, v, __ATOMIC_RELAXED, __HIP_MEMORY_SCOPE_AGENT);
}

__device__ __forceinline__ float waveRedSum(float v) {
#pragma unroll
  for (int off = 32; off; off >>= 1) v += __shfl_xor(v, off, 64);
  return v;
}
__device__ __forceinline__ float waveRedMax(float v) {
#pragma unroll
  for (int off = 32; off; off >>= 1) v = fmaxf(v, __shfl_xor(v, off, 64));
  return v;
}

#define UNPK(w, flo, fhi)                                     \
  float flo = __uint_as_float((unsigned)(w) << 16);           \
  float fhi = __uint_as_float((unsigned)(w) & 0xffff0000u);

// dot of 8 consecutive activations with a uint4 (8 bf16 weights)
__device__ __forceinline__ float dot8(const float *z, uint4 w) {
  UNPK(w.x, a0, a1); UNPK(w.y, b0, b1);
  UNPK(w.z, c0, c1); UNPK(w.w, d0, d1);
  return ((z[0] * a0 + z[1] * a1) + (z[2] * b0 + z[3] * b1)) +
         ((z[4] * c0 + z[5] * c1) + (z[6] * d0 + z[7] * d1));
}

// Group barrier: RELAXED arrive; waiters poll the arrive counter directly.
__device__ __forceinline__ void gbarN(unsigned *arr, unsigned &epoch,
                                      unsigned n) {
  __syncthreads();
  const unsigned e = ++epoch;
  if (threadIdx.x == 0) {
    __hip_atomic_fetch_add(arr, 1u, __ATOMIC_RELAXED,
                           __HIP_MEMORY_SCOPE_AGENT);
    while (__hip_atomic_load(arr, __ATOMIC_RELAXED,
                             __HIP_MEMORY_SCOPE_AGENT) < e * n)
      __builtin_amdgcn_s_sleep(1);
  }
  __syncthreads();
}

__global__ void ftkv_init(unsigned *bar) {
  for (int i = threadIdx.x; i < 4096; i += 256) bar[i] = 0u;
}

__device__ __forceinline__ unsigned bf16rne(float x) {
  unsigned b = __float_as_uint(x);
  return (b + 0x7fffu + ((b >> 16) & 1u)) >> 16;
}

// src[K][N] fp32 -> dst dwords laid out as [K/8][N][4]
__global__ void ftkv_pack(const float *src, unsigned *dst, int K, int N) {
  int total = (K / 2) * N;
  int n4 = N * 4;
  for (int i = blockIdx.x * blockDim.x + threadIdx.x; i < total;
       i += gridDim.x * blockDim.x) {
    int k8 = i / n4, rem = i - k8 * n4;
    int col = rem >> 2, q = rem & 3;
    int r0 = 8 * k8 + 2 * q;
    dst[i] = bf16rne(src[(size_t)r0 * N + col]) |
             (bf16rne(src[(size_t)(r0 + 1) * N + col]) << 16);
  }
}

#define LNSTATS(val, mu_, rs_)                                             \
  {                                                                        \
    __syncthreads();                                                       \
    if (tid < 512) {                                                       \
      float _s1 = waveRedSum(val), _s2 = waveRedSum((val) * (val));        \
      if (lane == 0) { sRed[wid] = _s1; sRed[8 + wid] = _s2; }             \
    }                                                                      \
    __syncthreads();                                                       \
    if (tid == 0) {                                                        \
      float _a = 0.f, _c = 0.f;                                            \
      for (int _i = 0; _i < 8; ++_i) { _a += sRed[_i]; _c += sRed[8 + _i];}\
      float _mu = _a * (1.f / 512.f);                                      \
      float _var = _c * (1.f / 512.f) - _mu * _mu;                         \
      sRed[16] = _mu; sRed[17] = rsqrtf(_var + 1e-5f);                     \
    }                                                                      \
    __syncthreads();                                                       \
    mu_ = sRed[16]; rs_ = sRed[17];                                        \
  }

__global__ __launch_bounds__(NTHR, 4) void ftkv_main(FtkvParams p) {
  const int bid = blockIdx.x;
  const int tid = threadIdx.x;
  const int lane = tid & 63, wid = tid >> 6;
  const int g = bid >> 3;  // batch element (group)
  const int cs = bid & 7;  // col-slice == head == XCD

  __shared__ float sZ[512];
  __shared__ float sP[1024];
  __shared__ float sH[256];
  __shared__ float sQ[64], sQB[64], sS[128], sRed[20];

  unsigned *garr = p.bar + g * 32;
  unsigned gep = 0;

  float cw0 = p.comb_w[0], cw1 = p.comb_w[1], cw2 = p.comb_w[2],
        cw3 = p.comb_w[3], cw4 = p.comb_w[4];
  float cm = fmaxf(fmaxf(fmaxf(cw0, cw1), fmaxf(cw2, cw3)), cw4);
  float e0 = __expf(cw0 - cm), e1 = __expf(cw1 - cm), e2 = __expf(cw2 - cm),
        e3 = __expf(cw3 - cm), e4 = __expf(cw4 - cm);
  float einv = 1.0f / (e0 + e1 + e2 + e3 + e4);
  float comb0 = e0 * einv, comb1 = e1 * einv, comb2 = e2 * einv,
        comb3 = e3 * einv, comb4 = e4 * einv;

  // full x and macc copies in lower 512 threads (tid == column)
  float xr = 0.f, mr = 0.f;
  if (tid < 512) {
    xr = p.x_seq[g * D_ + tid];
    mr = comb0 * xr;
  }

  unsigned *memKb = p.memK + ((size_t)(g * H_ + cs)) * S_ * 32;
  unsigned *memVb = p.memV + ((size_t)(g * H_ + cs)) * S_ * 32;

  for (int t = 0; t < S_; ++t) {
    for (int l = 0; l < L_; ++l) {
      // ---- entry update: apply FF(l-1) partials; macc += comb[l]*x ----
      if (l > 0 && tid < 512) {
        float s = p.b_ff2[(l - 1) * D_ + tid];
#pragma unroll
        for (int c2 = 0; c2 < 8; ++c2)
          s += cload(&p.dpart2[((size_t)g * 8 + c2) * D_ + tid]);
        xr += s;
        const float cl = (l == 1) ? comb1 : (l == 2) ? comb2 : comb3;
        mr += cl * xr;
      }

      // =================== Phase A: attention (t>0) =====================
      if (t > 0) {
        float mu, rs;
        LNSTATS(xr, mu, rs);
        if (tid < 512)
          sZ[tid] = (xr - mu) * rs * p.ln1_g[l * D_ + tid] +
                    p.ln1_b[l * D_ + tid];
        __syncthreads();
        // q projection: thread=(d=tid&63, ks=tid>>6 in 0..15), 4 uint4 each
        {
          int d = tid & 63, ks = tid >> 6;
          const uint4 *wq = p.wqp + (size_t)l * 64 * 512 + cs * 64 + d;
          float acc = 0.f;
#pragma unroll
          for (int j = 0; j < 4; ++j) {
            int k8 = ks * 4 + j;
            acc += dot8(&sZ[8 * k8], wq[(size_t)k8 * 512]);
          }
          sP[tid] = acc;
        }
        __syncthreads();
        if (tid < 64) {
          float q = 0.f;
#pragma unroll
          for (int ks = 0; ks < 16; ++ks) q += sP[ks * 64 + tid];
          sQ[tid] = q;
          sQB[tid] = q + p.qpb[(l * H_ + cs) * 64 + tid];
        }
        __syncthreads();
        // scores: thread=(j=tid&127, ds=tid>>7 in 0..7), 8 dims each
        {
          int j = tid & 127, ds = tid >> 7;
          float acc = 0.f;
          if (j < t) {
            uint4 mku = ((const uint4 *)(memKb + (size_t)j * 32))[ds];
            const float4 *kp = (const float4 *)(p.kpe +
                (((size_t)l * P_ + (P_ - t + j)) * H_ + cs) * 64 + ds * 8);
            float4 b0 = kp[0], b1 = kp[1];
            UNPK(mku.x, k0, k1); UNPK(mku.y, k2, k3);
            UNPK(mku.z, k4, k5); UNPK(mku.w, k6, k7);
            const float *qb = &sQB[ds * 8], *qr = &sQ[ds * 8];
            acc = (qb[0] * k0 + qb[1] * k1 + qb[2] * k2 + qb[3] * k3) +
                  (qb[4] * k4 + qb[5] * k5 + qb[6] * k6 + qb[7] * k7) +
                  (qr[0] * b0.x + qr[1] * b0.y + qr[2] * b0.z + qr[3] * b0.w) +
                  (qr[4] * b1.x + qr[5] * b1.y + qr[6] * b1.z + qr[7] * b1.w);
          }
          sP[tid] = acc;
        }
        __syncthreads();
        if (tid < 128) {
          float sc = ((sP[tid] + sP[tid + 128]) + (sP[tid + 256] + sP[tid + 384])) +
                     ((sP[tid + 512] + sP[tid + 640]) + (sP[tid + 768] + sP[tid + 896]));
          sS[tid] = (tid < t) ? sc * 0.125f : -1e30f;
        }
        __syncthreads();
        if (tid < 64) {
          float m = waveRedMax(fmaxf(sS[tid], sS[tid + 64]));
          if (tid == 0) sRed[18] = m;
        }
        __syncthreads();
        if (tid < 128)
          sS[tid] = (tid < t) ? __expf(sS[tid] - sRed[18]) : 0.f;
        __syncthreads();
        if (tid < 64) {
          float s = waveRedSum(sS[tid] + sS[tid + 64]);
          if (tid == 0) sRed[19] = s;
        }
        __syncthreads();
        // av: thread=(d=tid&63, js=tid>>6 in 0..15), 8 slots each
        {
          int d = tid & 63, js = tid >> 6;
          int j0 = js * 8, j1 = (j0 + 8 < t) ? (j0 + 8) : t;
          float acc = 0.f;
          const ushort *mv = (const ushort *)memVb;
          for (int j = j0; j < j1; ++j) {
            float vv = __uint_as_float(((unsigned)mv[(size_t)j * 64 + d]) << 16);
            acc += sS[j] * vv;
          }
          sP[tid] = acc;
        }
        __syncthreads();
        if (tid < 64) {
          float a = 0.f;
#pragma unroll
          for (int js = 0; js < 16; ++js) a += sP[js * 64 + tid];
          sQ[tid] = a / sRed[19];  // av (head cs)
        }
        __syncthreads();
        // Wout partial: thread=(col=tid&511, ks=tid>>9 in 0..1), 4 uint4
        {
          int col = tid & 511, ks = tid >> 9;
          const uint4 *wo = p.wop + (size_t)l * 64 * 512 + col;
          float acc = 0.f;
#pragma unroll
          for (int j = 0; j < 4; ++j) {
            int k8l = ks * 4 + j;
            acc += dot8(&sQ[8 * k8l], wo[(size_t)(cs * 8 + k8l) * 512]);
          }
          sP[tid] = acc;
        }
        __syncthreads();
        if (tid < 512)
          cstore(&p.dpart[((size_t)g * 8 + cs) * D_ + tid],
                 sP[tid] + sP[512 + tid]);
        gbarN(garr, gep, 8);
      }

      // =================== Phase B: out-proj apply + LN2 + FF ===========
      if (t > 0 && tid < 512) {
        float s = p.b_out[l * D_ + tid];
#pragma unroll
        for (int c2 = 0; c2 < 8; ++c2)
          s += cload(&p.dpart[((size_t)g * 8 + c2) * D_ + tid]);
        xr += s;
      }
      {
        float mu, rs;
        LNSTATS(xr, mu, rs);
        if (tid < 512)
          sZ[tid] = (xr - mu) * rs * p.ln2_g[l * D_ + tid] +
                    p.ln2_b[l * D_ + tid];
      }
      __syncthreads();
      // FF1: thread=(c=tid&255, ks=tid>>8 in 0..3), 16 uint4 each
      {
        int c = tid & 255, ks = tid >> 8;
        const uint4 *w1 = p.w1p + (size_t)l * 64 * DFF_ + cs * 256 + c;
        float acc = 0.f;
#pragma unroll 8
        for (int j = 0; j < 16; ++j) {
          int k8 = ks * 16 + j;
          acc += dot8(&sZ[8 * k8], w1[(size_t)k8 * DFF_]);
        }
        sP[tid] = acc;
      }
      __syncthreads();
      if (tid < 256) {
        float h = ((sP[tid] + sP[256 + tid]) + (sP[512 + tid] + sP[768 + tid])) +
                  p.b_ff1[l * DFF_ + cs * 256 + tid];
        sH[tid] = fmaxf(h, 0.f);
      }
      __syncthreads();
      // FF2 partial: thread=(col=tid&511, ks=tid>>9 in 0..1), 16 uint4
      {
        int col = tid & 511, ks = tid >> 9;
        const uint4 *w2 = p.w2p + (size_t)l * 256 * 512 + col;
        float acc = 0.f;
#pragma unroll 8
        for (int j = 0; j < 16; ++j) {
          int k8l = ks * 16 + j;
          acc += dot8(&sH[8 * k8l], w2[(size_t)(cs * 32 + k8l) * 512]);
        }
        sP[tid] = acc;
      }
      __syncthreads();
      if (tid < 512)
        cstore(&p.dpart2[((size_t)g * 8 + cs) * D_ + tid],
               sP[tid] + sP[512 + tid]);
      gbarN(garr, gep, 8);
    } // layers

    // ====== Phase E (group-local, no barrier): KV slot t; out; next x ====
    if (tid < 512) {
      float s = p.b_ff2[3 * D_ + tid];
#pragma unroll
      for (int c2 = 0; c2 < 8; ++c2)
        s += cload(&p.dpart2[((size_t)g * 8 + c2) * D_ + tid]);
      xr += s;
      mr += comb4 * xr;
      sZ[tid] = mr;
    }
    __syncthreads();
    // K/V proj: thread=(kv=tid>>9, r=tid&511 -> d=r&63, ks=r>>6), 8 uint4
    {
      int kv = tid >> 9, r = tid & 511, d = r & 63, ks = r >> 6;
      const uint4 *w4 = (kv ? p.wvp : p.wkp) + cs * 64 + d;
      float acc = 0.f;
#pragma unroll
      for (int j = 0; j < 8; ++j) {
        int k8 = ks * 8 + j;
        acc += dot8(&sZ[8 * k8], w4[(size_t)k8 * 512]);
      }
      sP[tid] = acc;
    }
    __syncthreads();
    if (tid < 128) {
      int kv = tid >> 6, d = tid & 63;
      float v = 0.f;
#pragma unroll
      for (int ks = 0; ks < 8; ++ks) v += sP[kv * 512 + ks * 64 + d];
      sS[tid] = v;  // stage fp32: [0..63]=K dims, [64..127]=V dims
    }
    __syncthreads();
    if (tid < 64) {
      int kv = tid >> 5, d2 = tid & 31;
      float lo = sS[kv * 64 + 2 * d2], hi = sS[kv * 64 + 2 * d2 + 1];
      unsigned pk = bf16rne(lo) | (bf16rne(hi) << 16);
      unsigned *dst = kv ? memVb : memKb;
      dst[(size_t)t * 32 + d2] = pk;
    }
    {
      float mu, rs;
      LNSTATS(xr, mu, rs);
      if (tid < 512 && (tid >> 6) == cs)
        p.out[((size_t)t * B_ + g) * D_ + tid] =
            (xr - mu) * rs * p.norm_g[tid] + p.norm_b[tid];
    }
    if (t + 1 < S_ && tid < 512) {
      xr = p.x_seq[((size_t)(t + 1) * B_ + g) * D_ + tid];
      mr = comb0 * xr;
    }
    // no barrier: E is group-local; next A-barrier orders everything
  } // t
}

extern "C" void kernel_launch(void *const *d_in, const int *in_sizes, int n_in,
                              void *d_out, int out_size, void *d_ws,
                              size_t ws_size, hipStream_t stream) {
  (void)in_sizes; (void)n_in; (void)out_size; (void)ws_size;

  FtkvParams p;
  p.x_seq  = (const float *)d_in[0];
  p.w_query = (const float *)d_in[1];
  p.qpb    = (const float *)d_in[2];
  p.kpe    = (const float *)d_in[3];
  p.w_out  = (const float *)d_in[4];
  p.b_out  = (const float *)d_in[5];
  p.ln1_g  = (const float *)d_in[6];
  p.ln1_b  = (const float *)d_in[7];
  p.ln2_g  = (const float *)d_in[8];
  p.ln2_b  = (const float *)d_in[9];
  p.w_ff1  = (const float *)d_in[10];
  p.b_ff1  = (const float *)d_in[11];
  p.w_ff2  = (const float *)d_in[12];
  p.b_ff2  = (const float *)d_in[13];
  p.norm_g = (const float *)d_in[14];
  p.norm_b = (const float *)d_in[15];
  p.comb_w = (const float *)d_in[16];
  p.w_key  = (const float *)d_in[17];
  p.w_value = (const float *)d_in[18];
  p.out = (float *)d_out;

  char *ws = (char *)d_ws;
  p.bar = (unsigned int *)ws; // 16KB
  float *f = (float *)(ws + 16384);
  p.dpart  = f; f += B_ * 8 * D_;
  p.dpart2 = f; f += B_ * 8 * D_;
  unsigned *u = (unsigned *)f;
  p.memK = u; u += B_ * H_ * S_ * 32;  // bf16-pair dwords
  p.memV = u; u += B_ * H_ * S_ * 32;
  unsigned *wqp = u; u += L_ * 256 * 512;
  unsigned *wop = u; u += L_ * 256 * 512;
  unsigned *w1p = u; u += L_ * 256 * DFF_;
  unsigned *w2p = u; u += L_ * 1024 * 512;
  unsigned *wkp = u; u += 256 * 512;
  unsigned *wvp = u; u += 256 * 512;
  p.wqp = (const uint4 *)wqp; p.wop = (const uint4 *)wop;
  p.w1p = (const uint4 *)w1p; p.w2p = (const uint4 *)w2p;
  p.wkp = (const uint4 *)wkp; p.wvp = (const uint4 *)wvp;

  ftkv_init<<<dim3(1), dim3(256), 0, stream>>>(p.bar);
  for (int l = 0; l < L_; ++l) {
    ftkv_pack<<<dim3(256), dim3(256), 0, stream>>>(
        p.w_query + (size_t)l * 512 * 512, wqp + (size_t)l * 256 * 512, 512, 512);
    ftkv_pack<<<dim3(256), dim3(256), 0, stream>>>(
        p.w_out + (size_t)l * 512 * 512, wop + (size_t)l * 256 * 512, 512, 512);
    ftkv_pack<<<dim3(512), dim3(256), 0, stream>>>(
        p.w_ff1 + (size_t)l * 512 * DFF_, w1p + (size_t)l * 256 * DFF_, 512, DFF_);
    ftkv_pack<<<dim3(512), dim3(256), 0, stream>>>(
        p.w_ff2 + (size_t)l * DFF_ * 512, w2p + (size_t)l * 1024 * 512, DFF_, 512);
  }
  ftkv_pack<<<dim3(256), dim3(256), 0, stream>>>(p.w_key, wkp, 512, 512);
  ftkv_pack<<<dim3(256), dim3(256), 0, stream>>>(p.w_value, wvp, 512, 512);
  ftkv_main<<<dim3(NBLK), dim3(NTHR), 0, stream>>>(p);
}